// Round 2
// baseline (1671.910 us; speedup 1.0000x reference)
//
#include <hip/hip_runtime.h>

#define NODES   64
#define FRAMES  4096
#define INCH    9
#define H1DIM   256
#define H2DIM   512
#define NEDGE   256

#define CHUNK   64
#define H1CP    72   // 72*4=288B row stride: 16B-aligned, non-pow2 (bank spread)

// ---------------------------------------------------------------------------
// prep: build CSR of normalized adjacency A (row = dst, self-loops included),
// zero the global accumulator. Handles int32 or int64 edge_index.
// ws layout: acc[512] f32 | rowptr[80] i32 | cols[512] i32 | vals[512] f32
// ---------------------------------------------------------------------------
__global__ void prep_kernel(const int* __restrict__ ei,
                            float* __restrict__ acc,
                            int* __restrict__ rowptrG,
                            int* __restrict__ colsG,
                            float* __restrict__ valsG)
{
    __shared__ float sA[NODES * NODES];
    __shared__ float dis[NODES];
    __shared__ int   deg[NODES];
    __shared__ int   cnt[NODES];
    __shared__ int   rp[NODES + 1];
    __shared__ int   flag;
    const int t = threadIdx.x;  // 256 threads
    if (t == 0) flag = 0;
    for (int i = t; i < NODES * NODES; i += 256) sA[i] = 0.f;
    if (t < NODES) deg[t] = 1;  // self-loop
    __syncthreads();
    // int64 little-endian => odd dwords are high words of values <64 => all 0.
    if (ei[2 * t + 1] != 0) atomicOr(&flag, 1);
    __syncthreads();
    const bool is64 = (flag == 0);
    int s = 0, d = 0;
    if (t < NEDGE) {
        if (is64) { s = ei[2 * t];   d = ei[512 + 2 * t]; }
        else      { s = ei[t];       d = ei[NEDGE + t];   }
        atomicAdd(&deg[d], 1);
    }
    __syncthreads();
    if (t < NODES) dis[t] = rsqrtf((float)deg[t]);
    __syncthreads();
    if (t < NEDGE) atomicAdd(&sA[d * NODES + s], dis[s] * dis[d]);  // row = dst
    __syncthreads();
    if (t < NODES) sA[t * NODES + t] += dis[t] * dis[t];
    __syncthreads();
    if (t < NODES) {
        int c = 0;
        for (int m = 0; m < NODES; ++m) if (sA[t * NODES + m] != 0.f) ++c;
        cnt[t] = c;
    }
    __syncthreads();
    if (t == 0) {
        rp[0] = 0;
        for (int n = 0; n < NODES; ++n) rp[n + 1] = rp[n] + cnt[n];
    }
    __syncthreads();
    if (t < NODES) {
        int base = rp[t];
        for (int m = 0; m < NODES; ++m) {
            float v = sA[t * NODES + m];
            if (v != 0.f) { colsG[base] = m; valsG[base] = v; ++base; }
        }
    }
    if (t <= NODES) rowptrG[t] = rp[t];
    for (int i = t; i < H2DIM; i += 256) acc[i] = 0.f;
}

// ---------------------------------------------------------------------------
// One block per frame. K-chunked (4 x 64) fused GCN:
//   per chunk: H1c = relu(AX@W1c + b1c) -> AH1c = A*H1c (sparse CSR)
//              -> a2[8][8] += AH1c @ W2[chunk rows]   (registers, persistent)
//   epilogue: relu(a2 + b2), row-sum, block-reduce, one global atomic / col.
// LDS ~49.4 KB -> 2 blocks/CU; launch_bounds caps VGPR at 128.
// ---------------------------------------------------------------------------
__global__ __launch_bounds__(512, 4)
void frame_kernel(const float* __restrict__ x,
                  const int* __restrict__ rowptrG,
                  const int* __restrict__ colsG,
                  const float* __restrict__ valsG,
                  const float* __restrict__ W1,
                  const float* __restrict__ b1,
                  const float* __restrict__ W2,
                  const float* __restrict__ b2,
                  float* __restrict__ acc)
{
    __shared__ int   sRp[NODES + 1];
    __shared__ int   sCol[512];
    __shared__ float sVal[512];
    __shared__ float sX [NODES][12];
    __shared__ float sAX[NODES][12];
    __shared__ __align__(16) float sH1c [NODES][H1CP];
    __shared__ __align__(16) float sAH1c[NODES][H1CP];
    __shared__ float sPart[H2DIM];

    const int t  = threadIdx.x;
    const int f  = blockIdx.x;
    const int wv = t >> 6;        // wave 0..7 -> rows 8wv..8wv+7
    const int ln = t & 63;        // lane      -> col group
    const int n0 = wv * 8;
    const int j0 = ln * 8;

    if (t <= NODES) sRp[t] = rowptrG[t];
    sCol[t]  = colsG[t];          // entries beyond nnz are never dereferenced
    sVal[t]  = valsG[t];
    sPart[t] = 0.f;
    for (int i = t; i < NODES * INCH; i += 512) {
        int n = i / INCH, c = i - n * INCH;
        sX[n][c] = x[(n * FRAMES + f) * INCH + c];
    }
    __syncthreads();

    // AX = A*X via CSR (diag included)
    for (int i = t; i < NODES * INCH; i += 512) {
        int n = i / INCH, c = i - n * INCH;
        float v = 0.f;
        const int p1 = sRp[n + 1];
        for (int p = sRp[n]; p < p1; ++p)
            v += sVal[p] * sX[sCol[p]][c];
        sAX[n][c] = v;
    }
    __syncthreads();

    float a2[8][8];
    #pragma unroll
    for (int r = 0; r < 8; ++r)
        #pragma unroll
        for (int cc = 0; cc < 8; ++cc) a2[r][cc] = 0.f;

    for (int ch = 0; ch < 4; ++ch) {
        const int jb = ch * CHUNK;

        // ---- layer1 chunk: H1c[n][ln] = relu(sum_c AX[n][c]*W1[c][jb+ln] + b1) ----
        {
            float h[8];
            const float bb = b1[jb + ln];
            #pragma unroll
            for (int r = 0; r < 8; ++r) h[r] = bb;
            #pragma unroll
            for (int c = 0; c < INCH; ++c) {
                const float w = W1[c * H1DIM + jb + ln];
                #pragma unroll
                for (int r = 0; r < 8; ++r)
                    h[r] = fmaf(sAX[n0 + r][c], w, h[r]);
            }
            #pragma unroll
            for (int r = 0; r < 8; ++r)
                sH1c[n0 + r][ln] = fmaxf(h[r], 0.f);
        }
        __syncthreads();

        // ---- sparse aggregation: AH1c[n][ln] = sum_nz val * H1c[col][ln] ----
        #pragma unroll
        for (int r = 0; r < 8; ++r) {
            const int n = n0 + r;
            float v = 0.f;
            const int p1 = sRp[n + 1];
            for (int p = sRp[n]; p < p1; ++p)
                v += sVal[p] * sH1c[sCol[p]][ln];
            sAH1c[n][ln] = v;
        }
        __syncthreads();

        // ---- GEMM chunk: a2[r][cc] += sum_k AH1c[n0+r][k] * W2[jb+k][j0+cc] ----
        for (int k0 = 0; k0 < CHUNK; k0 += 4) {
            float4 av[8];
            #pragma unroll
            for (int r = 0; r < 8; ++r)
                av[r] = *(const float4*)&sAH1c[n0 + r][k0];   // wave-uniform broadcast
            #pragma unroll
            for (int kk = 0; kk < 4; ++kk) {
                const float* wr = &W2[(jb + k0 + kk) * H2DIM + j0];
                const float4 w0 = *(const float4*)wr;
                const float4 w1 = *(const float4*)(wr + 4);
                const float wv8[8] = {w0.x, w0.y, w0.z, w0.w, w1.x, w1.y, w1.z, w1.w};
                #pragma unroll
                for (int r = 0; r < 8; ++r) {
                    const float a = (kk == 0) ? av[r].x : (kk == 1) ? av[r].y
                                  : (kk == 2) ? av[r].z : av[r].w;
                    #pragma unroll
                    for (int cc = 0; cc < 8; ++cc)
                        a2[r][cc] = fmaf(a, wv8[cc], a2[r][cc]);
                }
            }
        }
        __syncthreads();   // protect sH1c/sAH1c for next chunk
    }

    // ---- epilogue: relu + row-sum -> block partial -> global ----
    {
        const float4 bb0 = *(const float4*)&b2[j0];
        const float4 bb1 = *(const float4*)&b2[j0 + 4];
        const float bv[8] = {bb0.x, bb0.y, bb0.z, bb0.w, bb1.x, bb1.y, bb1.z, bb1.w};
        float s[8];
        #pragma unroll
        for (int cc = 0; cc < 8; ++cc) s[cc] = 0.f;
        #pragma unroll
        for (int r = 0; r < 8; ++r)
            #pragma unroll
            for (int cc = 0; cc < 8; ++cc)
                s[cc] += fmaxf(a2[r][cc] + bv[cc], 0.f);
        #pragma unroll
        for (int cc = 0; cc < 8; ++cc)
            atomicAdd(&sPart[j0 + cc], s[cc]);
    }
    __syncthreads();
    atomicAdd(&acc[t], sPart[t]);
}

// ---------------------------------------------------------------------------
// head: out[c] = (acc/262144) . Wfc[:,c] + bfc[c]
// ---------------------------------------------------------------------------
__global__ void head_kernel(const float* __restrict__ acc,
                            const float* __restrict__ Wfc,
                            const float* __restrict__ bfc,
                            float* __restrict__ out)
{
    const int c = blockIdx.x * 256 + threadIdx.x;
    if (c >= H2DIM) return;
    const float scale = 1.0f / (64.0f * 4096.0f);
    float v = bfc[c];
    for (int j = 0; j < H2DIM; ++j)
        v = fmaf(acc[j] * scale, Wfc[j * H2DIM + c], v);
    out[c] = v;
}

extern "C" void kernel_launch(void* const* d_in, const int* in_sizes, int n_in,
                              void* d_out, int out_size, void* d_ws, size_t ws_size,
                              hipStream_t stream)
{
    const float* x   = (const float*)d_in[0];
    const int*   ei  = (const int*)  d_in[1];
    const float* W1  = (const float*)d_in[2];
    const float* b1  = (const float*)d_in[3];
    const float* W2  = (const float*)d_in[4];
    const float* b2  = (const float*)d_in[5];
    const float* Wfc = (const float*)d_in[6];
    const float* bfc = (const float*)d_in[7];
    float* out = (float*)d_out;

    float* acc    = (float*)d_ws;            // 512 f32
    int*   rowptr = (int*)(acc + H2DIM);     // 80 i32 (65 used)
    int*   cols   = rowptr + 80;             // 512 i32
    float* vals   = (float*)(cols + 512);    // 512 f32

    prep_kernel <<<1,      256, 0, stream>>>(ei, acc, rowptr, cols, vals);
    frame_kernel<<<FRAMES, 512, 0, stream>>>(x, rowptr, cols, vals,
                                             W1, b1, W2, b2, acc);
    head_kernel <<<2,      256, 0, stream>>>(acc, Wfc, bfc, out);
}

// Round 3
// 920.344 us; speedup vs baseline: 1.8166x; 1.8166x over previous
//
#include <hip/hip_runtime.h>

#define NODES   64
#define FRAMES  4096
#define INCH    9
#define H1DIM   256
#define H2DIM   512
#define NEDGE   256

#define CHUNK   64
#define H1CP    72   // 72*4=288B row stride: 8B-aligned every row, non-pow2 (bank spread)

// ---------------------------------------------------------------------------
// prep: build CSR of normalized adjacency A (row = dst, self-loops included),
// zero the global accumulator. Handles int32 or int64 edge_index.
// ws layout: acc[512] f32 | rowptr[80] i32 | cols[512] i32 | vals[512] f32
// ---------------------------------------------------------------------------
__global__ void prep_kernel(const int* __restrict__ ei,
                            float* __restrict__ acc,
                            int* __restrict__ rowptrG,
                            int* __restrict__ colsG,
                            float* __restrict__ valsG)
{
    __shared__ float sA[NODES * NODES];
    __shared__ float dis[NODES];
    __shared__ int   deg[NODES];
    __shared__ int   cnt[NODES];
    __shared__ int   rp[NODES + 1];
    __shared__ int   flag;
    const int t = threadIdx.x;  // 256 threads
    if (t == 0) flag = 0;
    for (int i = t; i < NODES * NODES; i += 256) sA[i] = 0.f;
    if (t < NODES) deg[t] = 1;  // self-loop
    __syncthreads();
    // int64 little-endian => odd dwords are high words of values <64 => all 0.
    if (ei[2 * t + 1] != 0) atomicOr(&flag, 1);
    __syncthreads();
    const bool is64 = (flag == 0);
    int s = 0, d = 0;
    if (t < NEDGE) {
        if (is64) { s = ei[2 * t];   d = ei[512 + 2 * t]; }
        else      { s = ei[t];       d = ei[NEDGE + t];   }
        atomicAdd(&deg[d], 1);
    }
    __syncthreads();
    if (t < NODES) dis[t] = rsqrtf((float)deg[t]);
    __syncthreads();
    if (t < NEDGE) atomicAdd(&sA[d * NODES + s], dis[s] * dis[d]);  // row = dst
    __syncthreads();
    if (t < NODES) sA[t * NODES + t] += dis[t] * dis[t];
    __syncthreads();
    if (t < NODES) {
        int c = 0;
        for (int m = 0; m < NODES; ++m) if (sA[t * NODES + m] != 0.f) ++c;
        cnt[t] = c;
    }
    __syncthreads();
    if (t == 0) {
        rp[0] = 0;
        for (int n = 0; n < NODES; ++n) rp[n + 1] = rp[n] + cnt[n];
    }
    __syncthreads();
    if (t < NODES) {
        int base = rp[t];
        for (int m = 0; m < NODES; ++m) {
            float v = sA[t * NODES + m];
            if (v != 0.f) { colsG[base] = m; valsG[base] = v; ++base; }
        }
    }
    if (t <= NODES) rowptrG[t] = rp[t];
    for (int i = t; i < H2DIM; i += 256) acc[i] = 0.f;
}

// ---------------------------------------------------------------------------
// One block per frame. K-chunked (4 x 64) fused GCN:
//   per chunk: H1c = relu(AX@W1c + b1c) -> AH1c = A*H1c (sparse CSR)
//              -> a2[8][8] += AH1c @ W2[chunk rows]   (registers, persistent)
//   epilogue: relu(a2 + b2), row-sum, block-reduce, one global atomic / col.
// LDS ~49.4 KB -> 2 blocks/CU. launch_bounds(512,2): min 2 BLOCKS/CU (CUDA
// semantics, confirmed by round-2's 64-VGPR cap at arg2=4) -> 128 VGPR cap.
// Inner loop sized for ~105 live VGPRs -> no spill.
// ---------------------------------------------------------------------------
__global__ __launch_bounds__(512, 2)
void frame_kernel(const float* __restrict__ x,
                  const int* __restrict__ rowptrG,
                  const int* __restrict__ colsG,
                  const float* __restrict__ valsG,
                  const float* __restrict__ W1,
                  const float* __restrict__ b1,
                  const float* __restrict__ W2,
                  const float* __restrict__ b2,
                  float* __restrict__ acc)
{
    __shared__ int   sRp[NODES + 1];
    __shared__ int   sCol[512];
    __shared__ float sVal[512];
    __shared__ float sX [NODES][12];
    __shared__ float sAX[NODES][12];
    __shared__ __align__(16) float sH1c [NODES][H1CP];
    __shared__ __align__(16) float sAH1c[NODES][H1CP];
    __shared__ float sPart[H2DIM];

    const int t  = threadIdx.x;
    const int f  = blockIdx.x;
    const int wv = t >> 6;        // wave 0..7 -> rows 8wv..8wv+7
    const int ln = t & 63;        // lane      -> col group
    const int n0 = wv * 8;
    const int j0 = ln * 8;

    if (t <= NODES) sRp[t] = rowptrG[t];
    sCol[t]  = colsG[t];          // entries beyond nnz are never dereferenced
    sVal[t]  = valsG[t];
    sPart[t] = 0.f;
    for (int i = t; i < NODES * INCH; i += 512) {
        int n = i / INCH, c = i - n * INCH;
        sX[n][c] = x[(n * FRAMES + f) * INCH + c];
    }
    __syncthreads();

    // AX = A*X via CSR (diag included)
    for (int i = t; i < NODES * INCH; i += 512) {
        int n = i / INCH, c = i - n * INCH;
        float v = 0.f;
        const int p1 = sRp[n + 1];
        for (int p = sRp[n]; p < p1; ++p)
            v += sVal[p] * sX[sCol[p]][c];
        sAX[n][c] = v;
    }
    __syncthreads();

    float a2[8][8];
    #pragma unroll
    for (int r = 0; r < 8; ++r)
        #pragma unroll
        for (int cc = 0; cc < 8; ++cc) a2[r][cc] = 0.f;

    for (int ch = 0; ch < 4; ++ch) {
        const int jb = ch * CHUNK;

        // ---- layer1 chunk: H1c[n][ln] = relu(sum_c AX[n][c]*W1[c][jb+ln] + b1) ----
        {
            float h[8];
            const float bb = b1[jb + ln];
            #pragma unroll
            for (int r = 0; r < 8; ++r) h[r] = bb;
            #pragma unroll
            for (int c = 0; c < INCH; ++c) {
                const float w = W1[c * H1DIM + jb + ln];
                #pragma unroll
                for (int r = 0; r < 8; ++r)
                    h[r] = fmaf(sAX[n0 + r][c], w, h[r]);
            }
            #pragma unroll
            for (int r = 0; r < 8; ++r)
                sH1c[n0 + r][ln] = fmaxf(h[r], 0.f);
        }
        __syncthreads();

        // ---- sparse aggregation: AH1c[n][ln] = sum_nz val * H1c[col][ln] ----
        #pragma unroll
        for (int r = 0; r < 8; ++r) {
            const int n = n0 + r;
            float v = 0.f;
            const int p1 = sRp[n + 1];
            for (int p = sRp[n]; p < p1; ++p)
                v += sVal[p] * sH1c[sCol[p]][ln];
            sAH1c[n][ln] = v;
        }
        __syncthreads();

        // ---- GEMM chunk: a2[r][cc] += sum_k AH1c[n0+r][k] * W2[jb+k][j0+cc] ----
        // k-pairs: 8 broadcast ds_read_b64 + 4 global dwordx4 per 128 FMAs.
        const float* w2p = &W2[jb * H2DIM + j0];
        for (int k0 = 0; k0 < CHUNK; k0 += 2) {
            float2 av2[8];
            #pragma unroll
            for (int r = 0; r < 8; ++r)
                av2[r] = *(const float2*)&sAH1c[n0 + r][k0];   // wave-uniform broadcast
            #pragma unroll
            for (int kk = 0; kk < 2; ++kk) {
                const float4 w0 = *(const float4*)w2p;
                const float4 w1 = *(const float4*)(w2p + 4);
                w2p += H2DIM;
                const float wv8[8] = {w0.x, w0.y, w0.z, w0.w, w1.x, w1.y, w1.z, w1.w};
                #pragma unroll
                for (int r = 0; r < 8; ++r) {
                    const float a = kk ? av2[r].y : av2[r].x;
                    #pragma unroll
                    for (int cc = 0; cc < 8; ++cc)
                        a2[r][cc] = fmaf(a, wv8[cc], a2[r][cc]);
                }
            }
        }
        __syncthreads();   // protect sH1c/sAH1c for next chunk
    }

    // ---- epilogue: relu + row-sum -> block partial -> global ----
    {
        const float4 bb0 = *(const float4*)&b2[j0];
        const float4 bb1 = *(const float4*)&b2[j0 + 4];
        const float bv[8] = {bb0.x, bb0.y, bb0.z, bb0.w, bb1.x, bb1.y, bb1.z, bb1.w};
        float s[8];
        #pragma unroll
        for (int cc = 0; cc < 8; ++cc) s[cc] = 0.f;
        #pragma unroll
        for (int r = 0; r < 8; ++r)
            #pragma unroll
            for (int cc = 0; cc < 8; ++cc)
                s[cc] += fmaxf(a2[r][cc] + bv[cc], 0.f);
        #pragma unroll
        for (int cc = 0; cc < 8; ++cc)
            atomicAdd(&sPart[j0 + cc], s[cc]);
    }
    __syncthreads();
    atomicAdd(&acc[t], sPart[t]);
}

// ---------------------------------------------------------------------------
// head: out[c] = (acc/262144) . Wfc[:,c] + bfc[c]
// ---------------------------------------------------------------------------
__global__ void head_kernel(const float* __restrict__ acc,
                            const float* __restrict__ Wfc,
                            const float* __restrict__ bfc,
                            float* __restrict__ out)
{
    const int c = blockIdx.x * 256 + threadIdx.x;
    if (c >= H2DIM) return;
    const float scale = 1.0f / (64.0f * 4096.0f);
    float v = bfc[c];
    for (int j = 0; j < H2DIM; ++j)
        v = fmaf(acc[j] * scale, Wfc[j * H2DIM + c], v);
    out[c] = v;
}

extern "C" void kernel_launch(void* const* d_in, const int* in_sizes, int n_in,
                              void* d_out, int out_size, void* d_ws, size_t ws_size,
                              hipStream_t stream)
{
    const float* x   = (const float*)d_in[0];
    const int*   ei  = (const int*)  d_in[1];
    const float* W1  = (const float*)d_in[2];
    const float* b1  = (const float*)d_in[3];
    const float* W2  = (const float*)d_in[4];
    const float* b2  = (const float*)d_in[5];
    const float* Wfc = (const float*)d_in[6];
    const float* bfc = (const float*)d_in[7];
    float* out = (float*)d_out;

    float* acc    = (float*)d_ws;            // 512 f32
    int*   rowptr = (int*)(acc + H2DIM);     // 80 i32 (65 used)
    int*   cols   = rowptr + 80;             // 512 i32
    float* vals   = (float*)(cols + 512);    // 512 f32

    prep_kernel <<<1,      256, 0, stream>>>(ei, acc, rowptr, cols, vals);
    frame_kernel<<<FRAMES, 512, 0, stream>>>(x, rowptr, cols, vals,
                                             W1, b1, W2, b2, acc);
    head_kernel <<<2,      256, 0, stream>>>(acc, Wfc, bfc, out);
}